// Round 1
// baseline (296.804 us; speedup 1.0000x reference)
//
#include <hip/hip_runtime.h>
#include <hip/hip_bf16.h>
#include <stdint.h>

#define DEV __device__ __forceinline__

typedef __attribute__((ext_vector_type(8))) __bf16 bf16x8;
typedef __attribute__((ext_vector_type(4))) float f32x4;
typedef __attribute__((ext_vector_type(4))) short short4v;

constexpr int B_ = 4, S_ = 2048, D_ = 512, H_ = 8, DK_ = 64;
constexpr int M_ = B_ * S_;   // 8192 rows
constexpr int K_ = D_;        // 512 reduction dim for all projections

// RNE float->bf16 (finite inputs only)
DEV unsigned short f2bf(float f) {
  unsigned int u = __builtin_bit_cast(unsigned int, f);
  unsigned int r = (u + 0x7fffu + ((u >> 16) & 1u)) >> 16;
  return (unsigned short)r;
}

DEV void gld16(const void* g, void* l) {
  __builtin_amdgcn_global_load_lds(
      (const __attribute__((address_space(1))) unsigned int*)g,
      (__attribute__((address_space(3))) unsigned int*)l, 16, 0, 0);
}

DEV f32x4 mfma16(bf16x8 a, bf16x8 b, f32x4 c) {
  return __builtin_amdgcn_mfma_f32_16x16x32_bf16(a, b, c, 0, 0, 0);
}

// ---------------------------------------------------------------------------
// Kernel 1: convert all fp32 inputs to bf16 in workspace
// ---------------------------------------------------------------------------
__global__ __launch_bounds__(256) void convert_all(
    const float* __restrict__ q, const float* __restrict__ k, const float* __restrict__ v,
    const float* __restrict__ wq, const float* __restrict__ wk,
    const float* __restrict__ wv, const float* __restrict__ wo,
    unsigned short* __restrict__ xq, unsigned short* __restrict__ xk,
    unsigned short* __restrict__ xv, unsigned short* __restrict__ wqb,
    unsigned short* __restrict__ wkb, unsigned short* __restrict__ wvb,
    unsigned short* __restrict__ wob)
{
  constexpr int NX = M_ * D_;   // 4194304 = 2^22
  constexpr int NW = D_ * D_;   // 262144  = 2^18
  constexpr int TOT = (3 * NX + 4 * NW) / 4;
  for (int u = blockIdx.x * blockDim.x + threadIdx.x; u < TOT;
       u += gridDim.x * blockDim.x) {
    int e = u * 4;
    const float* src; unsigned short* dst; int off;
    if (e < 3 * NX) {
      int t = e >> 22; off = e & (NX - 1);
      src = (t == 0) ? q : ((t == 1) ? k : v);
      dst = (t == 0) ? xq : ((t == 1) ? xk : xv);
    } else {
      int e2 = e - 3 * NX;
      int t = e2 >> 18; off = e2 & (NW - 1);
      src = (t == 0) ? wq : ((t == 1) ? wk : ((t == 2) ? wv : wo));
      dst = (t == 0) ? wqb : ((t == 1) ? wkb : ((t == 2) ? wvb : wob));
    }
    float4 f = *(const float4*)(src + off);
    short4v o;
    o.x = (short)f2bf(f.x); o.y = (short)f2bf(f.y);
    o.z = (short)f2bf(f.z); o.w = (short)f2bf(f.w);
    *(short4v*)(dst + off) = o;
  }
}

// ---------------------------------------------------------------------------
// Kernel 2: C = A[M,K] @ W[N,K]^T  (both bf16 row-major, K-major => both tiles
// stage identically). BM=128, BN=64, BK=32; 4 waves in 2x2; wave tile 64x32.
// MODE 0: store bf16 head-split [B,H,S,DK].  MODE 1: fp32 + bias, [M,512].
// ---------------------------------------------------------------------------
template <int MODE>
__global__ __launch_bounds__(256, 2) void gemm_bt(
    const unsigned short* __restrict__ A, const unsigned short* __restrict__ W,
    unsigned short* __restrict__ outH, float* __restrict__ outF,
    const float* __restrict__ bias)
{
  constexpr int BM = 128, BN = 64, BK = 32;
  __shared__ unsigned short As[BM * BK];  // 8 KB
  __shared__ unsigned short Bs[BN * BK];  // 4 KB
  const int tid = threadIdx.x;
  const int lane = tid & 63, wave = tid >> 6;
  const int bn0 = blockIdx.x * BN, bm0 = blockIdx.y * BM;
  const int wr = (wave >> 1) * 64, wc = (wave & 1) * 32;
  const int frow = lane & 15, fk16 = (lane >> 4) * 16;  // k-chunk byte offset

  f32x4 zero = {0.f, 0.f, 0.f, 0.f};
  f32x4 acc[4][2];
#pragma unroll
  for (int i = 0; i < 4; ++i)
#pragma unroll
    for (int j = 0; j < 2; ++j) acc[i][j] = zero;

  for (int kt = 0; kt < K_ / BK; ++kt) {
    __syncthreads();
    // A tile 8 KB: rows bm0..+127, 64B per row slice
#pragma unroll
    for (int i = 0; i < 2; ++i) {
      int o = (wave * 2 + i) * 1024;
      int ol = o + lane * 16;
      gld16((const char*)A + (size_t)(bm0 + (ol >> 6)) * (K_ * 2) + kt * (BK * 2) + (ol & 63),
            (char*)As + o);
    }
    // B tile 4 KB
    {
      int o = wave * 1024;
      int ol = o + lane * 16;
      gld16((const char*)W + (size_t)(bn0 + (ol >> 6)) * (K_ * 2) + kt * (BK * 2) + (ol & 63),
            (char*)Bs + o);
    }
    __syncthreads();

    bf16x8 a[4], b[2];
#pragma unroll
    for (int i = 0; i < 4; ++i)
      a[i] = *(const bf16x8*)((const char*)As + (wr + i * 16 + frow) * 64 + fk16);
#pragma unroll
    for (int j = 0; j < 2; ++j)
      b[j] = *(const bf16x8*)((const char*)Bs + (wc + j * 16 + frow) * 64 + fk16);
#pragma unroll
    for (int i = 0; i < 4; ++i)
#pragma unroll
      for (int j = 0; j < 2; ++j)
        acc[i][j] = mfma16(a[i], b[j], acc[i][j]);
  }

  // epilogue: C/D layout col = lane&15, row = (lane>>4)*4 + reg  [m89/m91]
  const int r0 = (lane >> 4) * 4, cn = lane & 15;
#pragma unroll
  for (int i = 0; i < 4; ++i)
#pragma unroll
    for (int j = 0; j < 2; ++j)
#pragma unroll
      for (int r = 0; r < 4; ++r) {
        int gm = bm0 + wr + i * 16 + r0 + r;
        int gn = bn0 + wc + j * 16 + cn;
        float val = acc[i][j][r];
        if (MODE == 0) {
          int bb = gm >> 11, ss = gm & (S_ - 1), hh = gn >> 6, dk = gn & 63;
          outH[((size_t)(bb * H_ + hh) * S_ + ss) * DK_ + dk] = f2bf(val);
        } else {
          outF[(size_t)gm * D_ + gn] = val + bias[gn];
        }
      }
}

// ---------------------------------------------------------------------------
// Kernel 3: flash attention. Grid (S/128, B*H). 4 waves, 32 q-rows each.
// Q,K,V bf16 [B,H,S,64]; K_lds/Vt_lds/P_lds XOR-swizzled (row stride 128 B).
// ---------------------------------------------------------------------------
__global__ __launch_bounds__(256, 2) void attn(
    const unsigned short* __restrict__ Qb, const unsigned short* __restrict__ Kb,
    const unsigned short* __restrict__ Vb, unsigned short* __restrict__ Ctx)
{
  constexpr int QB = 128, KVB = 64;
  __shared__ unsigned short QP[QB * DK_];   // 16 KB: Q tile, later P tile
  __shared__ unsigned short Ks[KVB * DK_];  // 8 KB
  __shared__ unsigned short Vt[DK_ * KVB];  // 8 KB (transposed V: [d][k])
  const int tid = threadIdx.x, lane = tid & 63, wave = tid >> 6;
  const int bh = blockIdx.y;
  const int q0 = blockIdx.x * QB;
  const size_t hbase = (size_t)bh * S_ * DK_;
  const unsigned short* Qg = Qb + hbase + (size_t)q0 * DK_;
  const unsigned short* Kg = Kb + hbase;
  const unsigned short* Vg = Vb + hbase;
  const int frow = lane & 15, fk16 = (lane >> 4) * 16;

  // stage Q tile (16 KB, linear, contiguous in global)
#pragma unroll
  for (int i = 0; i < 4; ++i) {
    int o = (wave * 4 + i) * 1024;
    gld16((const char*)Qg + o + lane * 16, (char*)QP + o);
  }
  __syncthreads();
  bf16x8 qf[2][2];
#pragma unroll
  for (int qi = 0; qi < 2; ++qi)
#pragma unroll
    for (int kc = 0; kc < 2; ++kc)
      qf[qi][kc] = *(const bf16x8*)((const char*)QP +
                   (wave * 32 + qi * 16 + frow) * 128 + kc * 64 + fk16);

  f32x4 zero = {0.f, 0.f, 0.f, 0.f};
  f32x4 oacc[2][4];
  float mrun[2][4], lrun[2][4];
#pragma unroll
  for (int qi = 0; qi < 2; ++qi) {
#pragma unroll
    for (int d = 0; d < 4; ++d) oacc[qi][d] = zero;
#pragma unroll
    for (int r = 0; r < 4; ++r) { mrun[qi][r] = -1e30f; lrun[qi][r] = 0.f; }
  }

  for (int kv0 = 0; kv0 < S_; kv0 += KVB) {
    __syncthreads();  // previous tile fully consumed (also fences qf reads, iter 0)
    // stage K (8 KB) with PRE-SWIZZLED global source (rule 21): linear LDS dest,
    // source permuted by the same involution the reads apply.
#pragma unroll
    for (int i = 0; i < 2; ++i) {
      int o = (wave * 2 + i) * 1024;
      int ol = o + lane * 16;
      int src = ol ^ (((ol >> 7) & 7) << 4);
      gld16((const char*)Kg + (size_t)kv0 * (DK_ * 2) + src, (char*)Ks + o);
    }
    // stage V transposed: thread t covers row k=t>>2, 16 d's; swizzled writes
    {
      int kk = tid >> 2, dbase = (tid & 3) * 16;
      const char* vr = (const char*)Vg + ((size_t)(kv0 + kk) * DK_ + dbase) * 2;
      float4 v0 = *(const float4*)vr;
      float4 v1 = *(const float4*)(vr + 16);
      alignas(16) unsigned short tmp[16];
      *(float4*)&tmp[0] = v0;
      *(float4*)&tmp[8] = v1;
#pragma unroll
      for (int j = 0; j < 16; ++j) {
        int d = dbase + j;
        int byteoff = (d * 128 + kk * 2) ^ ((d & 7) << 4);
        *(unsigned short*)((char*)Vt + byteoff) = tmp[j];
      }
    }
    __syncthreads();

    // ---- QK^T: S[q][k], A=Q (row=q), B=K (col=k), both K-major ----
    f32x4 sacc[2][4];
#pragma unroll
    for (int qi = 0; qi < 2; ++qi)
#pragma unroll
      for (int kj = 0; kj < 4; ++kj) sacc[qi][kj] = zero;
#pragma unroll
    for (int kj = 0; kj < 4; ++kj) {
      bf16x8 kf[2];
#pragma unroll
      for (int kc = 0; kc < 2; ++kc) {
        int row = kj * 16 + frow;
        int off = (row * 128 + kc * 64 + fk16) ^ ((row & 7) << 4);
        kf[kc] = *(const bf16x8*)((const char*)Ks + off);
      }
#pragma unroll
      for (int qi = 0; qi < 2; ++qi)
#pragma unroll
        for (int kc = 0; kc < 2; ++kc)
          sacc[qi][kj] = mfma16(qf[qi][kc], kf[kc], sacc[qi][kj]);
    }

    // ---- online softmax: rows live on (lane>>4)*4+reg, cols on lane&15 ----
    constexpr float SC = 0.125f, L2E = 1.44269504f;
    float alpha[2][4];
#pragma unroll
    for (int qi = 0; qi < 2; ++qi) {
#pragma unroll
      for (int r = 0; r < 4; ++r) {
        float mx = fmaxf(fmaxf(sacc[qi][0][r], sacc[qi][1][r]),
                         fmaxf(sacc[qi][2][r], sacc[qi][3][r])) * SC;
        mx = fmaxf(mx, __shfl_xor(mx, 1));
        mx = fmaxf(mx, __shfl_xor(mx, 2));
        mx = fmaxf(mx, __shfl_xor(mx, 4));
        mx = fmaxf(mx, __shfl_xor(mx, 8));
        float mnew = fmaxf(mrun[qi][r], mx);
        float al = exp2f((mrun[qi][r] - mnew) * L2E);
        mrun[qi][r] = mnew;
        alpha[qi][r] = al;
        float psum = 0.f;
        int prow = wave * 32 + qi * 16 + (lane >> 4) * 4 + r;
#pragma unroll
        for (int kj = 0; kj < 4; ++kj) {
          float p = exp2f((sacc[qi][kj][r] * SC - mnew) * L2E);
          psum += p;
          int pcol = kj * 16 + (lane & 15);
          int off = (prow * 128 + pcol * 2) ^ ((prow & 7) << 4);
          *(unsigned short*)((char*)QP + off) = f2bf(p);
        }
        psum += __shfl_xor(psum, 1);
        psum += __shfl_xor(psum, 2);
        psum += __shfl_xor(psum, 4);
        psum += __shfl_xor(psum, 8);
        lrun[qi][r] = lrun[qi][r] * al + psum;
      }
    }
    // rescale running O
#pragma unroll
    for (int qi = 0; qi < 2; ++qi)
#pragma unroll
      for (int d = 0; d < 4; ++d)
#pragma unroll
        for (int r = 0; r < 4; ++r) oacc[qi][d][r] *= alpha[qi][r];

    asm volatile("s_waitcnt lgkmcnt(0)" ::: "memory");  // P writes drained (intra-wave)

    // ---- PV: A=P[q][k] (own rows, intra-wave), B=Vt (col=d) ----
#pragma unroll
    for (int kc = 0; kc < 2; ++kc) {
      bf16x8 pa[2], vb[4];
#pragma unroll
      for (int qi = 0; qi < 2; ++qi) {
        int prow = wave * 32 + qi * 16 + frow;
        int off = (prow * 128 + kc * 64 + fk16) ^ ((prow & 7) << 4);
        pa[qi] = *(const bf16x8*)((const char*)QP + off);
      }
#pragma unroll
      for (int df = 0; df < 4; ++df) {
        int drow = df * 16 + frow;
        int off = (drow * 128 + kc * 64 + fk16) ^ ((drow & 7) << 4);
        vb[df] = *(const bf16x8*)((const char*)Vt + off);
      }
#pragma unroll
      for (int qi = 0; qi < 2; ++qi)
#pragma unroll
        for (int df = 0; df < 4; ++df)
          oacc[qi][df] = mfma16(pa[qi], vb[df], oacc[qi][df]);
    }
  }

  // epilogue: ctx bf16 in merged [B,S,D] layout
  const int bq = bh >> 3, hh = bh & 7;
#pragma unroll
  for (int qi = 0; qi < 2; ++qi)
#pragma unroll
    for (int r = 0; r < 4; ++r) {
      float inv = 1.f / lrun[qi][r];
      int qrow = q0 + wave * 32 + qi * 16 + (lane >> 4) * 4 + r;
#pragma unroll
      for (int df = 0; df < 4; ++df) {
        int d = hh * 64 + df * 16 + (lane & 15);
        Ctx[((size_t)bq * S_ + qrow) * D_ + d] = f2bf(oacc[qi][df][r] * inv);
      }
    }
}

// ---------------------------------------------------------------------------
extern "C" void kernel_launch(void* const* d_in, const int* in_sizes, int n_in,
                              void* d_out, int out_size, void* d_ws, size_t ws_size,
                              hipStream_t stream) {
  const float* q  = (const float*)d_in[0];
  const float* k  = (const float*)d_in[1];
  const float* v  = (const float*)d_in[2];
  const float* wq = (const float*)d_in[3];
  const float* wk = (const float*)d_in[4];
  const float* wv = (const float*)d_in[5];
  const float* wo = (const float*)d_in[6];
  const float* bo = (const float*)d_in[7];
  float* out = (float*)d_out;

  constexpr size_t NX = (size_t)M_ * D_;  // 4194304 elems
  constexpr size_t NW = (size_t)D_ * D_;  // 262144 elems
  char* ws = (char*)d_ws;                 // ~58.5 MB used total
  unsigned short* Xq  = (unsigned short*)ws; ws += NX * 2;
  unsigned short* Xk  = (unsigned short*)ws; ws += NX * 2;
  unsigned short* Xv  = (unsigned short*)ws; ws += NX * 2;
  unsigned short* Wqb = (unsigned short*)ws; ws += NW * 2;
  unsigned short* Wkb = (unsigned short*)ws; ws += NW * 2;
  unsigned short* Wvb = (unsigned short*)ws; ws += NW * 2;
  unsigned short* Wob = (unsigned short*)ws; ws += NW * 2;
  unsigned short* Qbf = (unsigned short*)ws; ws += NX * 2;
  unsigned short* Kbf = (unsigned short*)ws; ws += NX * 2;
  unsigned short* Vbf = (unsigned short*)ws; ws += NX * 2;
  unsigned short* Cx  = (unsigned short*)ws; ws += NX * 2;

  convert_all<<<2048, 256, 0, stream>>>(q, k, v, wq, wk, wv, wo,
                                        Xq, Xk, Xv, Wqb, Wkb, Wvb, Wob);
  dim3 ggrid(D_ / 64, M_ / 128);
  gemm_bt<0><<<ggrid, 256, 0, stream>>>(Xq, Wqb, Qbf, nullptr, nullptr);
  gemm_bt<0><<<ggrid, 256, 0, stream>>>(Xk, Wkb, Kbf, nullptr, nullptr);
  gemm_bt<0><<<ggrid, 256, 0, stream>>>(Xv, Wvb, Vbf, nullptr, nullptr);
  attn<<<dim3(S_ / 128, B_ * H_), 256, 0, stream>>>(Qbf, Kbf, Vbf, Cx);
  gemm_bt<1><<<ggrid, 256, 0, stream>>>(Cx, Wob, nullptr, out, bo);
}

// Round 2
// 212.782 us; speedup vs baseline: 1.3949x; 1.3949x over previous
//
#include <hip/hip_runtime.h>
#include <hip/hip_bf16.h>
#include <stdint.h>

#define DEV __device__ __forceinline__

typedef __attribute__((ext_vector_type(8))) __bf16 bf16x8;
typedef __attribute__((ext_vector_type(4))) float f32x4;
typedef __attribute__((ext_vector_type(16))) float f32x16;
typedef __attribute__((ext_vector_type(4))) short short4v;
typedef __attribute__((ext_vector_type(8))) short short8v;
typedef __attribute__((ext_vector_type(4))) unsigned int uint4v;

constexpr int B_ = 4, S_ = 2048, D_ = 512, H_ = 8, DK_ = 64;
constexpr int M_ = B_ * S_;   // 8192
constexpr int K_ = D_;        // 512

// RNE float->bf16 (finite inputs only)
DEV unsigned short f2bf(float f) {
  unsigned int u = __builtin_bit_cast(unsigned int, f);
  unsigned int r = (u + 0x7fffu + ((u >> 16) & 1u)) >> 16;
  return (unsigned short)r;
}

DEV void gld16(const void* g, void* l) {
  __builtin_amdgcn_global_load_lds(
      (const __attribute__((address_space(1))) unsigned int*)g,
      (__attribute__((address_space(3))) unsigned int*)l, 16, 0, 0);
}

DEV f32x4 mfma16(bf16x8 a, bf16x8 b, f32x4 c) {
  return __builtin_amdgcn_mfma_f32_16x16x32_bf16(a, b, c, 0, 0, 0);
}
DEV f32x16 mfma32(bf16x8 a, bf16x8 b, f32x16 c) {
  return __builtin_amdgcn_mfma_f32_32x32x16_bf16(a, b, c, 0, 0, 0);
}

// ds_read_b64_tr_b16: 16-lane group reads a 128B window (4x16 bf16 subtile),
// lane m of group gets column m. vaddr = window_base + (lane&15)*8.
DEV short4v tr16(const void* p) {
  short4v d;
  asm volatile("ds_read_b64_tr_b16 %0, %1"
               : "=v"(d)
               : "v"((const __attribute__((address_space(3))) char*)p));
  return d;
}

DEV unsigned pkbf(float a, float b) {  // dword = {lo: bf16(a), hi: bf16(b)}
  unsigned r;
  asm("v_cvt_pk_bf16_f32 %0, %1, %2" : "=v"(r) : "v"(a), "v"(b));
  return r;
}

DEV void pl32swap(unsigned& a, unsigned& b) {
  // a[32:63] <-> b[0:31]
  asm volatile("v_permlane32_swap_b32 %0, %1" : "+v"(a), "+v"(b));
}

// ---------------------------------------------------------------------------
// Kernel 1: convert all fp32 inputs to bf16 in workspace
// ---------------------------------------------------------------------------
__global__ __launch_bounds__(256) void convert_all(
    const float* __restrict__ q, const float* __restrict__ k, const float* __restrict__ v,
    const float* __restrict__ wq, const float* __restrict__ wk,
    const float* __restrict__ wv, const float* __restrict__ wo,
    unsigned short* __restrict__ xq, unsigned short* __restrict__ xk,
    unsigned short* __restrict__ xv, unsigned short* __restrict__ wqb,
    unsigned short* __restrict__ wkb, unsigned short* __restrict__ wvb,
    unsigned short* __restrict__ wob)
{
  constexpr int NX = M_ * D_;   // 2^22
  constexpr int NW = D_ * D_;   // 2^18
  constexpr int TOT = (3 * NX + 4 * NW) / 4;
  for (int u = blockIdx.x * blockDim.x + threadIdx.x; u < TOT;
       u += gridDim.x * blockDim.x) {
    int e = u * 4;
    const float* src; unsigned short* dst; int off;
    if (e < 3 * NX) {
      int t = e >> 22; off = e & (NX - 1);
      src = (t == 0) ? q : ((t == 1) ? k : v);
      dst = (t == 0) ? xq : ((t == 1) ? xk : xv);
    } else {
      int e2 = e - 3 * NX;
      int t = e2 >> 18; off = e2 & (NW - 1);
      src = (t == 0) ? wq : ((t == 1) ? wk : ((t == 2) ? wv : wo));
      dst = (t == 0) ? wqb : ((t == 1) ? wkb : ((t == 2) ? wvb : wob));
    }
    float4 f = *(const float4*)(src + off);
    short4v o;
    o.x = (short)f2bf(f.x); o.y = (short)f2bf(f.y);
    o.z = (short)f2bf(f.z); o.w = (short)f2bf(f.w);
    *(short4v*)(dst + off) = o;
  }
}

// ---------------------------------------------------------------------------
// Kernel 2: C = A[M,K] @ W[N,K]^T. BM=128, BN=64, BK=64; double-buffered LDS,
// 1 barrier/iter; XOR-swizzled tiles (rows are 128B). 4 waves 2x2, 64x32 each.
// MODE 0: bf16 head-split [B,H,S,DK].  MODE 1: fp32 + bias, [M,512].
// ---------------------------------------------------------------------------
template <int MODE>
__global__ __launch_bounds__(256, 2) void gemm_bt(
    const unsigned short* __restrict__ A, const unsigned short* __restrict__ W,
    unsigned short* __restrict__ outH, float* __restrict__ outF,
    const float* __restrict__ bias)
{
  constexpr int BM = 128, BN = 64, BK = 64, NKT = K_ / BK;
  __shared__ unsigned short As[2][BM * BK];  // 2 x 16 KB
  __shared__ unsigned short Bs[2][BN * BK];  // 2 x 8 KB
  const int tid = threadIdx.x, lane = tid & 63, wave = tid >> 6;
  const int bn0 = blockIdx.x * BN, bm0 = blockIdx.y * BM;
  const int wr = (wave >> 1) * 64, wc = (wave & 1) * 32;
  const int frow = lane & 15, fk16 = (lane >> 4) * 16;

  f32x4 acc[4][2];
#pragma unroll
  for (int i = 0; i < 4; ++i)
#pragma unroll
    for (int j = 0; j < 2; ++j)
#pragma unroll
      for (int r = 0; r < 4; ++r) acc[i][j][r] = 0.f;

  auto stage = [&](int kt, int buf) {
#pragma unroll
    for (int i = 0; i < 4; ++i) {  // A: 16 KB
      int o = (wave * 4 + i) * 1024;
      int ol = o + lane * 16;
      int src = ol ^ (((ol >> 7) & 7) << 4);
      gld16((const char*)A + (size_t)(bm0 + (src >> 7)) * (K_ * 2) + kt * 128 + (src & 127),
            (char*)As[buf] + o);
    }
#pragma unroll
    for (int i = 0; i < 2; ++i) {  // B: 8 KB
      int o = (wave * 2 + i) * 1024;
      int ol = o + lane * 16;
      int src = ol ^ (((ol >> 7) & 7) << 4);
      gld16((const char*)W + (size_t)(bn0 + (src >> 7)) * (K_ * 2) + kt * 128 + (src & 127),
            (char*)Bs[buf] + o);
    }
  };

  stage(0, 0);
  __syncthreads();
  int cur = 0;
  for (int kt = 0; kt < NKT; ++kt) {
    if (kt + 1 < NKT) stage(kt + 1, cur ^ 1);
#pragma unroll
    for (int kc = 0; kc < 2; ++kc) {
      bf16x8 a[4], b[2];
#pragma unroll
      for (int i = 0; i < 4; ++i) {
        int row = wr + i * 16 + frow;
        a[i] = *(const bf16x8*)((const char*)As[cur] +
                ((row * 128 + kc * 64 + fk16) ^ ((row & 7) << 4)));
      }
#pragma unroll
      for (int j = 0; j < 2; ++j) {
        int row = wc + j * 16 + frow;
        b[j] = *(const bf16x8*)((const char*)Bs[cur] +
                ((row * 128 + kc * 64 + fk16) ^ ((row & 7) << 4)));
      }
      __builtin_amdgcn_s_setprio(1);
#pragma unroll
      for (int i = 0; i < 4; ++i)
#pragma unroll
        for (int j = 0; j < 2; ++j)
          acc[i][j] = mfma16(a[i], b[j], acc[i][j]);
      __builtin_amdgcn_s_setprio(0);
    }
    __syncthreads();
    cur ^= 1;
  }

  // epilogue: C/D layout col = lane&15, row = (lane>>4)*4 + reg
  const int r0 = (lane >> 4) * 4, cn = lane & 15;
#pragma unroll
  for (int i = 0; i < 4; ++i)
#pragma unroll
    for (int j = 0; j < 2; ++j)
#pragma unroll
      for (int r = 0; r < 4; ++r) {
        int gm = bm0 + wr + i * 16 + r0 + r;
        int gn = bn0 + wc + j * 16 + cn;
        float val = acc[i][j][r];
        if (MODE == 0) {
          int bb = gm >> 11, ss = gm & (S_ - 1), hh = gn >> 6, dk = gn & 63;
          outH[((size_t)(bb * H_ + hh) * S_ + ss) * DK_ + dk] = f2bf(val);
        } else {
          outF[(size_t)gm * D_ + gn] = val + bias[gn];
        }
      }
}

// ---------------------------------------------------------------------------
// Kernel 3: flash attention, 32x32 MFMA, swapped QK^T, in-register softmax.
// Grid (S/128, B*H); 4 waves x 32 q-rows. KVB=64, K/V double-buffered.
// K: [64][64] XOR-swizzled rows. V: subtiled [k/4][d/16][4][16] for tr16.
// ---------------------------------------------------------------------------
__global__ __launch_bounds__(256, 2) void attn(
    const unsigned short* __restrict__ Qb, const unsigned short* __restrict__ Kb,
    const unsigned short* __restrict__ Vb, unsigned short* __restrict__ Ctx)
{
  constexpr int QB = 128, KVB = 64, NT = S_ / KVB;
  __shared__ unsigned short Qs[QB * DK_];      // 16 KB (swizzled rows)
  __shared__ unsigned short Kd[2][KVB * DK_];  // 2 x 8 KB (swizzled rows)
  __shared__ unsigned short Vd[2][KVB * DK_];  // 2 x 8 KB (subtiled)
  __shared__ float smA[4][32];                 // per-wave alpha / inv-l bcast
  const int tid = threadIdx.x, lane = tid & 63, wave = tid >> 6;
  const int hi = lane >> 5, l31 = lane & 31, g1 = (lane >> 4) & 1;
  const int bh = blockIdx.y, q0 = blockIdx.x * QB;
  const size_t hb = (size_t)bh * S_ * DK_;
  const char* Qg = (const char*)(Qb + hb + (size_t)q0 * DK_);
  const char* Kg = (const char*)(Kb + hb);
  const char* Vg = (const char*)(Vb + hb);

  auto stageSwz = [&](const char* gbase, unsigned short* lds, int o) {
    int ol = o + lane * 16;
    int src = ol ^ (((ol >> 7) & 7) << 4);
    gld16(gbase + src, (char*)lds + o);
  };
  auto stageVt = [&](const char* gbase, unsigned short* lds, int o) {
    int ol = o + lane * 16;
    int E0 = ol >> 1;                       // first bf16 elem index
    int st = E0 >> 6, rr = (E0 >> 4) & 3, c0 = E0 & 15;
    int kk = (st >> 2) * 4 + rr, dd = (st & 3) * 16 + c0;
    gld16(gbase + (kk * DK_ + dd) * 2, (char*)lds + o);
  };

  // prologue: stage Q + tile 0
#pragma unroll
  for (int i = 0; i < 4; ++i) stageSwz(Qg, Qs, (wave * 4 + i) * 1024);
#pragma unroll
  for (int i = 0; i < 2; ++i) stageSwz(Kg, Kd[0], (wave * 2 + i) * 1024);
#pragma unroll
  for (int i = 0; i < 2; ++i) stageVt(Vg, Vd[0], (wave * 2 + i) * 1024);
  __syncthreads();

  // Q fragments (B-operand): row = wave*32 + l31, elems d = c*16 + hi*8 + e
  bf16x8 qf[4];
  {
    int row = wave * 32 + l31;
    int rb = row * 128, sw = (row & 7) << 4;
#pragma unroll
    for (int c = 0; c < 4; ++c)
      qf[c] = *(const bf16x8*)((const char*)Qs + ((rb + c * 32 + hi * 16) ^ sw));
  }

  f32x16 oacc[2];
#pragma unroll
  for (int dt = 0; dt < 2; ++dt)
#pragma unroll
    for (int r = 0; r < 16; ++r) oacc[dt][r] = 0.f;
  float m2 = -1e30f, lsum = 0.f;
  constexpr float SCL2 = 0.125f * 1.44269504089f;  // 1/sqrt(DK) * log2(e)

  int cur = 0;
  for (int t = 0; t < NT; ++t) {
    if (t + 1 < NT) {
      const char* Kg1 = Kg + (size_t)(t + 1) * (KVB * DK_ * 2);
      const char* Vg1 = Vg + (size_t)(t + 1) * (KVB * DK_ * 2);
#pragma unroll
      for (int i = 0; i < 2; ++i) stageSwz(Kg1, Kd[cur ^ 1], (wave * 2 + i) * 1024);
#pragma unroll
      for (int i = 0; i < 2; ++i) stageVt(Vg1, Vd[cur ^ 1], (wave * 2 + i) * 1024);
    }

    // ---- swapped QK^T: sacc[kt2] = K_tile * Q^T ; S^T[k][q] ----
    f32x16 sacc[2];
#pragma unroll
    for (int k2 = 0; k2 < 2; ++k2)
#pragma unroll
      for (int r = 0; r < 16; ++r) sacc[k2][r] = 0.f;
    __builtin_amdgcn_s_setprio(1);
#pragma unroll
    for (int c = 0; c < 4; ++c) {
#pragma unroll
      for (int k2 = 0; k2 < 2; ++k2) {
        int row = k2 * 32 + l31;
        bf16x8 kf = *(const bf16x8*)((const char*)Kd[cur] +
                     ((row * 128 + c * 32 + hi * 16) ^ ((row & 7) << 4)));
        sacc[k2] = mfma32(kf, qf[c], sacc[k2]);
      }
    }
    __builtin_amdgcn_s_setprio(0);

    // ---- in-register online softmax (q = l31; lane holds 32 of 64 k's) ----
    float mloc = sacc[0][0];
#pragma unroll
    for (int k2 = 0; k2 < 2; ++k2)
#pragma unroll
      for (int r = 0; r < 16; ++r) mloc = fmaxf(mloc, sacc[k2][r]);
    mloc = fmaxf(mloc, __shfl_xor(mloc, 32));
    float m2n = fmaxf(m2, mloc * SCL2);
    float alpha = __builtin_amdgcn_exp2f(m2 - m2n);
    m2 = m2n;
    float psum = 0.f;
#pragma unroll
    for (int k2 = 0; k2 < 2; ++k2)
#pragma unroll
      for (int r = 0; r < 16; ++r) {
        float p = __builtin_amdgcn_exp2f(fmaf(sacc[k2][r], SCL2, -m2n));
        sacc[k2][r] = p;
        psum += p;
      }
    psum += __shfl_xor(psum, 32);
    lsum = lsum * alpha + psum;

    // broadcast alpha[q] to O-layout lanes via per-wave LDS row
    if (lane < 32) smA[wave][lane] = alpha;
    f32x4 av[4];
#pragma unroll
    for (int s = 0; s < 4; ++s)
      av[s] = *(const f32x4*)&smA[wave][s * 8 + hi * 4];
#pragma unroll
    for (int dt = 0; dt < 2; ++dt)
#pragma unroll
      for (int r = 0; r < 16; ++r) oacc[dt][r] *= av[r >> 2][r & 3];

    // ---- PV: issue all V tr-reads, build P-frags (hides ds latency) ----
    short4v va[4][2][2];
#pragma unroll
    for (int c = 0; c < 4; ++c)
#pragma unroll
      for (int dt = 0; dt < 2; ++dt) {
        int st = 16 * c + 8 * hi + 2 * dt + g1;
        const char* ad = (const char*)Vd[cur] + st * 128 + (lane & 15) * 8;
        va[c][dt][0] = tr16(ad);
        va[c][dt][1] = tr16(ad + 512);
      }
    bf16x8 pfrag[4];
#pragma unroll
    for (int c = 0; c < 4; ++c) {
      const f32x16& P = sacc[c >> 1];
      const int b = (c & 1) * 8;
      unsigned d0 = pkbf(P[b + 0], P[b + 1]);
      unsigned d1 = pkbf(P[b + 2], P[b + 3]);
      unsigned d2 = pkbf(P[b + 4], P[b + 5]);
      unsigned d3 = pkbf(P[b + 6], P[b + 7]);
      pl32swap(d0, d2);
      pl32swap(d1, d3);
      uint4v pi = {d0, d1, d2, d3};
      pfrag[c] = __builtin_bit_cast(bf16x8, pi);
    }
    asm volatile("s_waitcnt lgkmcnt(0)" ::: "memory");
    __builtin_amdgcn_sched_barrier(0);
    __builtin_amdgcn_s_setprio(1);
#pragma unroll
    for (int c = 0; c < 4; ++c)
#pragma unroll
      for (int dt = 0; dt < 2; ++dt) {
        short8v vv = __builtin_shufflevector(va[c][dt][0], va[c][dt][1],
                                             0, 1, 2, 3, 4, 5, 6, 7);
        oacc[dt] = mfma32(pfrag[c], __builtin_bit_cast(bf16x8, vv), oacc[dt]);
      }
    __builtin_amdgcn_s_setprio(0);

    __syncthreads();  // drains vmcnt: next K/V tile ready; cur safe to overwrite
    cur ^= 1;
  }

  // epilogue: O[q][d], q = (r&3)+8*(r>>2)+4*hi, d = dt*32 + l31
  if (lane < 32) smA[wave][lane] = 1.f / lsum;
  f32x4 iv[4];
#pragma unroll
  for (int s = 0; s < 4; ++s)
    iv[s] = *(const f32x4*)&smA[wave][s * 8 + hi * 4];
  const int bq = bh >> 3, hh = bh & 7;
#pragma unroll
  for (int dt = 0; dt < 2; ++dt)
#pragma unroll
    for (int r = 0; r < 16; ++r) {
      int qq = (r & 3) + 8 * (r >> 2) + 4 * hi;
      int grow = q0 + wave * 32 + qq;
      int col = hh * 64 + dt * 32 + l31;
      Ctx[((size_t)bq * S_ + grow) * D_ + col] = f2bf(oacc[dt][r] * iv[r >> 2][r & 3]);
    }
}

// ---------------------------------------------------------------------------
extern "C" void kernel_launch(void* const* d_in, const int* in_sizes, int n_in,
                              void* d_out, int out_size, void* d_ws, size_t ws_size,
                              hipStream_t stream) {
  const float* q  = (const float*)d_in[0];
  const float* k  = (const float*)d_in[1];
  const float* v  = (const float*)d_in[2];
  const float* wq = (const float*)d_in[3];
  const float* wk = (const float*)d_in[4];
  const float* wv = (const float*)d_in[5];
  const float* wo = (const float*)d_in[6];
  const float* bo = (const float*)d_in[7];
  float* out = (float*)d_out;

  constexpr size_t NX = (size_t)M_ * D_;
  constexpr size_t NW = (size_t)D_ * D_;
  char* ws = (char*)d_ws;
  unsigned short* Xq  = (unsigned short*)ws; ws += NX * 2;
  unsigned short* Xk  = (unsigned short*)ws; ws += NX * 2;
  unsigned short* Xv  = (unsigned short*)ws; ws += NX * 2;
  unsigned short* Wqb = (unsigned short*)ws; ws += NW * 2;
  unsigned short* Wkb = (unsigned short*)ws; ws += NW * 2;
  unsigned short* Wvb = (unsigned short*)ws; ws += NW * 2;
  unsigned short* Wob = (unsigned short*)ws; ws += NW * 2;
  unsigned short* Qbf = (unsigned short*)ws; ws += NX * 2;
  unsigned short* Kbf = (unsigned short*)ws; ws += NX * 2;
  unsigned short* Vbf = (unsigned short*)ws; ws += NX * 2;
  unsigned short* Cx  = (unsigned short*)ws; ws += NX * 2;

  convert_all<<<2048, 256, 0, stream>>>(q, k, v, wq, wk, wv, wo,
                                        Xq, Xk, Xv, Wqb, Wkb, Wvb, Wob);
  dim3 ggrid(D_ / 64, M_ / 128);
  gemm_bt<0><<<ggrid, 256, 0, stream>>>(Xq, Wqb, Qbf, nullptr, nullptr);
  gemm_bt<0><<<ggrid, 256, 0, stream>>>(Xk, Wkb, Kbf, nullptr, nullptr);
  gemm_bt<0><<<ggrid, 256, 0, stream>>>(Xv, Wvb, Vbf, nullptr, nullptr);
  attn<<<dim3(S_ / 128, B_ * H_), 256, 0, stream>>>(Qbf, Kbf, Vbf, Cx);
  gemm_bt<1><<<ggrid, 256, 0, stream>>>(Cx, Wob, nullptr, out, bo);
}

// Round 4
// 201.926 us; speedup vs baseline: 1.4699x; 1.0538x over previous
//
#include <hip/hip_runtime.h>
#include <hip/hip_bf16.h>
#include <stdint.h>

#define DEV __device__ __forceinline__

typedef __attribute__((ext_vector_type(8))) __bf16 bf16x8;
typedef __attribute__((ext_vector_type(4))) float f32x4;
typedef __attribute__((ext_vector_type(16))) float f32x16;
typedef __attribute__((ext_vector_type(4))) short short4v;
typedef __attribute__((ext_vector_type(8))) short short8v;
typedef __attribute__((ext_vector_type(4))) unsigned int uint4v;

constexpr int B_ = 4, S_ = 2048, D_ = 512, H_ = 8, DK_ = 64;
constexpr int M_ = B_ * S_;   // 8192
constexpr int K_ = D_;        // 512

// RNE float->bf16 (finite inputs only)
DEV unsigned short f2bf(float f) {
  unsigned int u = __builtin_bit_cast(unsigned int, f);
  unsigned int r = (u + 0x7fffu + ((u >> 16) & 1u)) >> 16;
  return (unsigned short)r;
}

DEV void gld16(const void* g, void* l) {
  __builtin_amdgcn_global_load_lds(
      (const __attribute__((address_space(1))) unsigned int*)g,
      (__attribute__((address_space(3))) unsigned int*)l, 16, 0, 0);
}

DEV f32x4 mfma16(bf16x8 a, bf16x8 b, f32x4 c) {
  return __builtin_amdgcn_mfma_f32_16x16x32_bf16(a, b, c, 0, 0, 0);
}
DEV f32x16 mfma32(bf16x8 a, bf16x8 b, f32x16 c) {
  return __builtin_amdgcn_mfma_f32_32x32x16_bf16(a, b, c, 0, 0, 0);
}

// ds_read_b64_tr_b16: 16-lane group reads a 128B window (4x16 bf16 subtile),
// lane m of group gets column m.
DEV short4v tr16(const void* p) {
  short4v d;
  asm volatile("ds_read_b64_tr_b16 %0, %1"
               : "=v"(d)
               : "v"((const __attribute__((address_space(3))) char*)p));
  return d;
}

DEV unsigned pkbf(float a, float b) {  // dword = {lo: bf16(a), hi: bf16(b)}
  unsigned r;
  asm("v_cvt_pk_bf16_f32 %0, %1, %2" : "=v"(r) : "v"(a), "v"(b));
  return r;
}

DEV void pl32swap(unsigned& a, unsigned& b) {  // a[32:63] <-> b[0:31]
  asm volatile("v_permlane32_swap_b32 %0, %1" : "+v"(a), "+v"(b));
}

// ---------------------------------------------------------------------------
// Kernel 1: convert all fp32 inputs to bf16 in workspace
// ---------------------------------------------------------------------------
__global__ __launch_bounds__(256) void convert_all(
    const float* __restrict__ q, const float* __restrict__ k, const float* __restrict__ v,
    const float* __restrict__ wq, const float* __restrict__ wk,
    const float* __restrict__ wv, const float* __restrict__ wo,
    unsigned short* __restrict__ xq, unsigned short* __restrict__ xk,
    unsigned short* __restrict__ xv, unsigned short* __restrict__ wqb,
    unsigned short* __restrict__ wkb, unsigned short* __restrict__ wvb,
    unsigned short* __restrict__ wob)
{
  constexpr int NX = M_ * D_;   // 2^22
  constexpr int NW = D_ * D_;   // 2^18
  constexpr int TOT = (3 * NX + 4 * NW) / 4;
  for (int u = blockIdx.x * blockDim.x + threadIdx.x; u < TOT;
       u += gridDim.x * blockDim.x) {
    int e = u * 4;
    const float* src; unsigned short* dst; int off;
    if (e < 3 * NX) {
      int t = e >> 22; off = e & (NX - 1);
      src = (t == 0) ? q : ((t == 1) ? k : v);
      dst = (t == 0) ? xq : ((t == 1) ? xk : xv);
    } else {
      int e2 = e - 3 * NX;
      int t = e2 >> 18; off = e2 & (NW - 1);
      src = (t == 0) ? wq : ((t == 1) ? wk : ((t == 2) ? wv : wo));
      dst = (t == 0) ? wqb : ((t == 1) ? wkb : ((t == 2) ? wvb : wob));
    }
    float4 f = *(const float4*)(src + off);
    short4v o;
    o.x = (short)f2bf(f.x); o.y = (short)f2bf(f.y);
    o.z = (short)f2bf(f.z); o.w = (short)f2bf(f.w);
    *(short4v*)(dst + off) = o;
  }
}

// ---------------------------------------------------------------------------
// Kernel 2: C = A[M,K] @ W[N,K]^T, bf16, XOR-swizzled dbuf LDS, 1 barrier/iter.
// MODE 0: BM=128, grid (4,64,3) — fused Q/K/V projections, bf16 out [M,512].
// MODE 1: BM=64,  grid (4,128)  — output projection, fp32 + bias out [M,512].
// BN=128, BK=64. 4 waves 2x2; wave tile (BM/2)x64.
// ---------------------------------------------------------------------------
template <int MODE>
__global__ __launch_bounds__(256, 2) void gemm_bt(
    const unsigned short* __restrict__ A0, const unsigned short* __restrict__ A1,
    const unsigned short* __restrict__ A2,
    const unsigned short* __restrict__ W0, const unsigned short* __restrict__ W1,
    const unsigned short* __restrict__ W2,
    unsigned short* __restrict__ O0, unsigned short* __restrict__ O1,
    unsigned short* __restrict__ O2,
    float* __restrict__ outF, const float* __restrict__ bias)
{
  constexpr int BM = (MODE == 0) ? 128 : 64;
  constexpr int BN = 128, BK = 64, NKT = K_ / BK;
  constexpr int AFR = BM / 32;  // a-frags per wave
  __shared__ unsigned short As[2][BM * BK];
  __shared__ unsigned short Bs[2][BN * BK];
  const int tid = threadIdx.x, lane = tid & 63, wave = tid >> 6;
  const int z = blockIdx.z;
  const unsigned short* A = (MODE == 1 || z == 0) ? A0 : (z == 1 ? A1 : A2);
  const unsigned short* W = (MODE == 1 || z == 0) ? W0 : (z == 1 ? W1 : W2);
  unsigned short* outH = (MODE == 1 || z == 0) ? O0 : (z == 1 ? O1 : O2);
  const int bn0 = blockIdx.x * BN, bm0 = blockIdx.y * BM;
  const int wr = (wave >> 1) * (BM / 2), wc = (wave & 1) * 64;
  const int frow = lane & 15, fk16 = (lane >> 4) * 16;

  f32x4 acc[AFR][4];
#pragma unroll
  for (int i = 0; i < AFR; ++i)
#pragma unroll
    for (int j = 0; j < 4; ++j)
#pragma unroll
      for (int r = 0; r < 4; ++r) acc[i][j][r] = 0.f;

  auto stage = [&](int kt, int buf) {
#pragma unroll
    for (int i = 0; i < BM / 32; ++i) {  // A tile: BM*128 bytes
      int o = (wave * (BM / 32) + i) * 1024;
      int ol = o + lane * 16;
      int row = ol >> 7, off = (ol ^ ((row & 7) << 4)) & 127;
      gld16((const char*)A + (size_t)(bm0 + row) * (K_ * 2) + kt * 128 + off,
            (char*)As[buf] + o);
    }
#pragma unroll
    for (int i = 0; i < 4; ++i) {        // B tile: 16 KB
      int o = (wave * 4 + i) * 1024;
      int ol = o + lane * 16;
      int row = ol >> 7, off = (ol ^ ((row & 7) << 4)) & 127;
      gld16((const char*)W + (size_t)(bn0 + row) * (K_ * 2) + kt * 128 + off,
            (char*)Bs[buf] + o);
    }
  };

  stage(0, 0);
  __syncthreads();
  int cur = 0;
  for (int kt = 0; kt < NKT; ++kt) {
    if (kt + 1 < NKT) stage(kt + 1, cur ^ 1);
#pragma unroll
    for (int kc = 0; kc < 2; ++kc) {
      bf16x8 a[AFR], b[4];
#pragma unroll
      for (int i = 0; i < AFR; ++i) {
        int row = wr + i * 16 + frow;
        a[i] = *(const bf16x8*)((const char*)As[cur] +
                ((row * 128 + kc * 64 + fk16) ^ ((row & 7) << 4)));
      }
#pragma unroll
      for (int j = 0; j < 4; ++j) {
        int row = wc + j * 16 + frow;
        b[j] = *(const bf16x8*)((const char*)Bs[cur] +
                ((row * 128 + kc * 64 + fk16) ^ ((row & 7) << 4)));
      }
      __builtin_amdgcn_s_setprio(1);
#pragma unroll
      for (int i = 0; i < AFR; ++i)
#pragma unroll
        for (int j = 0; j < 4; ++j)
          acc[i][j] = mfma16(a[i], b[j], acc[i][j]);
      __builtin_amdgcn_s_setprio(0);
    }
    __syncthreads();
    cur ^= 1;
  }

  // epilogue: C/D layout col = lane&15, row = (lane>>4)*4 + reg
  const int r0 = (lane >> 4) * 4, cn = lane & 15;
  float bv[4];
  if (MODE == 1) {
#pragma unroll
    for (int j = 0; j < 4; ++j) bv[j] = bias[bn0 + wc + j * 16 + cn];
  }
#pragma unroll
  for (int i = 0; i < AFR; ++i)
#pragma unroll
    for (int j = 0; j < 4; ++j)
#pragma unroll
      for (int r = 0; r < 4; ++r) {
        int gm = bm0 + wr + i * 16 + r0 + r;
        int gn = bn0 + wc + j * 16 + cn;
        float val = acc[i][j][r];
        if (MODE == 0) outH[(size_t)gm * D_ + gn] = f2bf(val);
        else           outF[(size_t)gm * D_ + gn] = val + bv[j];
      }
}

// ---------------------------------------------------------------------------
// Kernel 3: flash attention, 32x32 MFMA, swapped QK^T, in-register softmax
// (round-2 proven core: unconditional rescale, shfl_xor cross-half).
// Q/K/V in [M,512] layout, head h at cols h*64..h*64+63 (row stride 1024 B).
// Grid (S/128, B*H); 4 waves x 32 q-rows. KVB=64, K/V double-buffered.
// ---------------------------------------------------------------------------
__global__ __launch_bounds__(256, 2) void attn(
    const unsigned short* __restrict__ Qm, const unsigned short* __restrict__ Km,
    const unsigned short* __restrict__ Vm, unsigned short* __restrict__ Ctx)
{
  constexpr int QB = 128, KVB = 64, NT = S_ / KVB;
  __shared__ unsigned short Qs[QB * DK_];      // 16 KB (swizzled rows)
  __shared__ unsigned short Kd[2][KVB * DK_];  // 2 x 8 KB (swizzled rows)
  __shared__ unsigned short Vd[2][KVB * DK_];  // 2 x 8 KB (subtiled for tr16)
  __shared__ float smA[4][32];                 // per-wave bcast row
  const int tid = threadIdx.x, lane = tid & 63, wave = tid >> 6;
  const int hi = lane >> 5, l31 = lane & 31, g1 = (lane >> 4) & 1;
  const int bh = blockIdx.y, q0 = blockIdx.x * QB;
  const int bq = bh >> 3, hh = bh & 7;
  const char* Qg = (const char*)(Qm + ((size_t)bq * S_ + q0) * D_ + hh * DK_);
  const char* Kg = (const char*)(Km + (size_t)bq * S_ * D_ + hh * DK_);
  const char* Vg = (const char*)(Vm + (size_t)bq * S_ * D_ + hh * DK_);

  // stage 128B-row tile from row-stride-1024B global into swizzled LDS
  auto stageSwz = [&](const char* gbase, unsigned short* lds, int o) {
    int ol = o + lane * 16;
    int row = ol >> 7, off = (ol ^ ((row & 7) << 4)) & 127;
    gld16(gbase + (size_t)row * 1024 + off, (char*)lds + o);
  };
  auto stageVt = [&](const char* gbase, unsigned short* lds, int o) {
    int ol = o + lane * 16;
    int E0 = ol >> 1;
    int st = E0 >> 6, rr = (E0 >> 4) & 3, c0 = E0 & 15;
    int kk = (st >> 2) * 4 + rr, dd = (st & 3) * 16 + c0;
    gld16(gbase + (size_t)kk * 1024 + dd * 2, (char*)lds + o);
  };

  // prologue: stage Q (128 rows) + tile 0
#pragma unroll
  for (int i = 0; i < 4; ++i) stageSwz(Qg, Qs, (wave * 4 + i) * 1024);
#pragma unroll
  for (int i = 0; i < 2; ++i) stageSwz(Kg, Kd[0], (wave * 2 + i) * 1024);
#pragma unroll
  for (int i = 0; i < 2; ++i) stageVt(Vg, Vd[0], (wave * 2 + i) * 1024);
  __syncthreads();

  // Q fragments (B-operand): row = wave*32 + l31, elems d = c*16 + hi*8 + e
  bf16x8 qf[4];
  {
    int row = wave * 32 + l31;
    int rb = row * 128, sw = (row & 7) << 4;
#pragma unroll
    for (int c = 0; c < 4; ++c)
      qf[c] = *(const bf16x8*)((const char*)Qs + ((rb + c * 32 + hi * 16) ^ sw));
  }

  f32x16 oacc[2];
#pragma unroll
  for (int dt = 0; dt < 2; ++dt)
#pragma unroll
    for (int r = 0; r < 16; ++r) oacc[dt][r] = 0.f;
  float m2 = -1e30f, lsum = 0.f;
  constexpr float SCL2 = 0.125f * 1.44269504089f;  // 1/sqrt(DK) * log2(e)

  int cur = 0;
  for (int t = 0; t < NT; ++t) {
    if (t + 1 < NT) {
      const char* Kg1 = Kg + (size_t)(t + 1) * KVB * 1024;
      const char* Vg1 = Vg + (size_t)(t + 1) * KVB * 1024;
#pragma unroll
      for (int i = 0; i < 2; ++i) stageSwz(Kg1, Kd[cur ^ 1], (wave * 2 + i) * 1024);
#pragma unroll
      for (int i = 0; i < 2; ++i) stageVt(Vg1, Vd[cur ^ 1], (wave * 2 + i) * 1024);
    }

    // ---- swapped QK^T: sacc[k2] = K_tile * Q^T (S^T[k][q], q = l31) ----
    f32x16 sacc[2];
#pragma unroll
    for (int k2 = 0; k2 < 2; ++k2)
#pragma unroll
      for (int r = 0; r < 16; ++r) sacc[k2][r] = 0.f;
    __builtin_amdgcn_s_setprio(1);
#pragma unroll
    for (int c = 0; c < 4; ++c) {
#pragma unroll
      for (int k2 = 0; k2 < 2; ++k2) {
        int row = k2 * 32 + l31;
        bf16x8 kf = *(const bf16x8*)((const char*)Kd[cur] +
                     ((row * 128 + c * 32 + hi * 16) ^ ((row & 7) << 4)));
        sacc[k2] = mfma32(kf, qf[c], sacc[k2]);
      }
    }
    __builtin_amdgcn_s_setprio(0);

    // ---- online softmax (round-2 core: unconditional rescale) ----
    float mloc = sacc[0][0];
#pragma unroll
    for (int k2 = 0; k2 < 2; ++k2)
#pragma unroll
      for (int r = 0; r < 16; ++r) mloc = fmaxf(mloc, sacc[k2][r]);
    mloc = fmaxf(mloc, __shfl_xor(mloc, 32));
    float m2n = fmaxf(m2, mloc * SCL2);
    float alpha = __builtin_amdgcn_exp2f(m2 - m2n);
    m2 = m2n;
    float psum = 0.f;
#pragma unroll
    for (int k2 = 0; k2 < 2; ++k2)
#pragma unroll
      for (int r = 0; r < 16; ++r) {
        float p = __builtin_amdgcn_exp2f(fmaf(sacc[k2][r], SCL2, -m2n));
        sacc[k2][r] = p;
        psum += p;
      }
    psum += __shfl_xor(psum, 32);
    lsum = lsum * alpha + psum;

    // broadcast alpha[q] to O-layout lanes via per-wave LDS row
    if (lane < 32) smA[wave][lane] = alpha;
    f32x4 av[4];
#pragma unroll
    for (int s = 0; s < 4; ++s)
      av[s] = *(const f32x4*)&smA[wave][s * 8 + hi * 4];
#pragma unroll
    for (int dt = 0; dt < 2; ++dt)
#pragma unroll
      for (int r = 0; r < 16; ++r) oacc[dt][r] *= av[r >> 2][r & 3];

    // ---- PV: issue V tr-reads, build P-frags while ds in flight ----
    short4v va[4][2][2];
#pragma unroll
    for (int c = 0; c < 4; ++c)
#pragma unroll
      for (int dt = 0; dt < 2; ++dt) {
        int st = 16 * c + 8 * hi + 2 * dt + g1;
        const char* ad = (const char*)Vd[cur] + st * 128 + (lane & 15) * 8;
        va[c][dt][0] = tr16(ad);
        va[c][dt][1] = tr16(ad + 512);
      }
    bf16x8 pfrag[4];
#pragma unroll
    for (int c = 0; c < 4; ++c) {
      const f32x16& P = sacc[c >> 1];
      const int b = (c & 1) * 8;
      unsigned d0 = pkbf(P[b + 0], P[b + 1]);
      unsigned d1 = pkbf(P[b + 2], P[b + 3]);
      unsigned d2 = pkbf(P[b + 4], P[b + 5]);
      unsigned d3 = pkbf(P[b + 6], P[b + 7]);
      pl32swap(d0, d2);
      pl32swap(d1, d3);
      uint4v pi = {d0, d1, d2, d3};
      pfrag[c] = __builtin_bit_cast(bf16x8, pi);
    }
    asm volatile("s_waitcnt lgkmcnt(0)" ::: "memory");
    __builtin_amdgcn_sched_barrier(0);
    __builtin_amdgcn_s_setprio(1);
#pragma unroll
    for (int c = 0; c < 4; ++c)
#pragma unroll
      for (int dt = 0; dt < 2; ++dt) {
        short8v vv = __builtin_shufflevector(va[c][dt][0], va[c][dt][1],
                                             0, 1, 2, 3, 4, 5, 6, 7);
        oacc[dt] = mfma32(pfrag[c], __builtin_bit_cast(bf16x8, vv), oacc[dt]);
      }
    __builtin_amdgcn_s_setprio(0);

    __syncthreads();  // next K/V tile staged; cur safe to overwrite
    cur ^= 1;
  }

  // epilogue: O[q][d], q = (r&3)+8*(r>>2)+4*hi, d = dt*32 + l31
  if (lane < 32) smA[wave][lane] = 1.f / lsum;
  f32x4 iv[4];
#pragma unroll
  for (int s = 0; s < 4; ++s)
    iv[s] = *(const f32x4*)&smA[wave][s * 8 + hi * 4];
#pragma unroll
  for (int dt = 0; dt < 2; ++dt)
#pragma unroll
    for (int r = 0; r < 16; ++r) {
      int qq = (r & 3) + 8 * (r >> 2) + 4 * hi;
      int grow = q0 + wave * 32 + qq;
      int col = hh * 64 + dt * 32 + l31;
      Ctx[((size_t)bq * S_ + grow) * D_ + col] = f2bf(oacc[dt][r] * iv[r >> 2][r & 3]);
    }
}

// ---------------------------------------------------------------------------
extern "C" void kernel_launch(void* const* d_in, const int* in_sizes, int n_in,
                              void* d_out, int out_size, void* d_ws, size_t ws_size,
                              hipStream_t stream) {
  const float* q  = (const float*)d_in[0];
  const float* k  = (const float*)d_in[1];
  const float* v  = (const float*)d_in[2];
  const float* wq = (const float*)d_in[3];
  const float* wk = (const float*)d_in[4];
  const float* wv = (const float*)d_in[5];
  const float* wo = (const float*)d_in[6];
  const float* bo = (const float*)d_in[7];
  float* out = (float*)d_out;

  constexpr size_t NX = (size_t)M_ * D_;
  constexpr size_t NW = (size_t)D_ * D_;
  char* ws = (char*)d_ws;
  unsigned short* Xq  = (unsigned short*)ws; ws += NX * 2;
  unsigned short* Xk  = (unsigned short*)ws; ws += NX * 2;
  unsigned short* Xv  = (unsigned short*)ws; ws += NX * 2;
  unsigned short* Wqb = (unsigned short*)ws; ws += NW * 2;
  unsigned short* Wkb = (unsigned short*)ws; ws += NW * 2;
  unsigned short* Wvb = (unsigned short*)ws; ws += NW * 2;
  unsigned short* Wob = (unsigned short*)ws; ws += NW * 2;
  unsigned short* Qbf = (unsigned short*)ws; ws += NX * 2;
  unsigned short* Kbf = (unsigned short*)ws; ws += NX * 2;
  unsigned short* Vbf = (unsigned short*)ws; ws += NX * 2;
  unsigned short* Cx  = (unsigned short*)ws; ws += NX * 2;

  convert_all<<<2048, 256, 0, stream>>>(q, k, v, wq, wk, wv, wo,
                                        Xq, Xk, Xv, Wqb, Wkb, Wvb, Wob);
  gemm_bt<0><<<dim3(4, 64, 3), 256, 0, stream>>>(
      Xq, Xk, Xv, Wqb, Wkb, Wvb, Qbf, Kbf, Vbf, nullptr, nullptr);
  attn<<<dim3(S_ / 128, B_ * H_), 256, 0, stream>>>(Qbf, Kbf, Vbf, Cx);
  gemm_bt<1><<<dim3(4, 128, 1), 256, 0, stream>>>(
      Cx, nullptr, nullptr, Wob, nullptr, nullptr, nullptr, nullptr, nullptr,
      out, bo);
}